// Round 1
// baseline (199.246 us; speedup 1.0000x reference)
//
#include <hip/hip_runtime.h>

#define BS 16
#define V  2048
#define C  512
#define PN 512
#define K  16
#define NT 256

// One block per (batch, sampled row). Phase 1: all 2048 distances -> packed
// (dist,idx) keys in LDS. Phase 2: 16 rounds of block-wide argmin (matches
// jax top_k tie-break: lower index wins on equal distance; self excluded ==
// reference's "drop top-1 of 17" since self-distance is the unique 0 minimum).
// Phase 3: gather 16 feature rows (coalesced, 2KiB each) and channel-wise max.
__global__ __launch_bounds__(NT) void pool_knn_kernel(
    const float* __restrict__ vert,   // [BS, V, 3]
    const float* __restrict__ feat,   // [BS, V, C]
    const int*   __restrict__ sidx,   // [PN]
    float* __restrict__ out)          // [BS*PN*3] ++ [BS*PN*C]
{
    const int blk = blockIdx.x;
    const int b = blk >> 9;          // / PN
    const int s = blk & (PN - 1);
    const int t = threadIdx.x;

    const int q = sidx[s];
    const float* vb = vert + (size_t)b * (V * 3);
    const float qx = vb[q * 3 + 0];
    const float qy = vb[q * 3 + 1];
    const float qz = vb[q * 3 + 2];
    // quadratic[n] (same arithmetic order as reference's sum(v*v, axis=2))
    const float qq = qx * qx + qy * qy + qz * qz;

    __shared__ unsigned long long keys[V];     // 16 KiB
    __shared__ unsigned long long wmin[NT / 64];
    __shared__ int nbr[K];

    // ---- Phase 1: distances ----
    for (int m = t; m < V; m += NT) {
        const float mx = vb[m * 3 + 0];
        const float my = vb[m * 3 + 1];
        const float mz = vb[m * 3 + 2];
        const float qm = mx * mx + my * my + mz * mz;
        const float inner = qx * mx + qy * my + qz * mz;
        // reference: ((-2*inner) + quad[m]) + quad[n]; -2*x is exact so fma
        // contraction on the first add cannot change the rounding.
        const float dist = (-2.0f * inner + qm) + qq;
        // order-preserving float->uint map (handles tiny negatives safely)
        unsigned u = __float_as_uint(dist);
        u ^= (u & 0x80000000u) ? 0xFFFFFFFFu : 0x80000000u;
        unsigned long long key = ((unsigned long long)u << 32) | (unsigned)m;
        if (m == q) key = ~0ULL;               // exclude self
        keys[m] = key;
    }
    __syncthreads();

    // ---- Phase 2: 16 x block argmin with knockout ----
    for (int r = 0; r < K; ++r) {
        unsigned long long mn = ~0ULL;
        #pragma unroll
        for (int i = 0; i < V / NT; ++i) {
            const unsigned long long v2 = keys[t + i * NT];
            mn = (v2 < mn) ? v2 : mn;
        }
        #pragma unroll
        for (int off = 32; off > 0; off >>= 1) {
            const unsigned long long o = __shfl_down(mn, off);
            mn = (o < mn) ? o : mn;
        }
        if ((t & 63) == 0) wmin[t >> 6] = mn;
        __syncthreads();
        if (t == 0) {
            unsigned long long bm = wmin[0];
            #pragma unroll
            for (int w = 1; w < NT / 64; ++w) bm = (wmin[w] < bm) ? wmin[w] : bm;
            const int widx = (int)(bm & 0xFFFFFFFFu);
            nbr[r] = widx;
            keys[widx] = ~0ULL;                // knock out for next round
        }
        __syncthreads();
    }

    // ---- Phase 3: gather + channel max ----
    const float* fb = feat + (size_t)b * (V * C);
    const int ch = t * 2;                      // 2 channels/thread, coalesced
    float m0 = -__builtin_inff(), m1 = -__builtin_inff();
    #pragma unroll
    for (int r = 0; r < K; ++r) {
        const float2 f = *reinterpret_cast<const float2*>(fb + (size_t)nbr[r] * C + ch);
        m0 = fmaxf(m0, f.x);
        m1 = fmaxf(m1, f.y);
    }
    float* o1 = out + (size_t)BS * PN * 3 + (size_t)(b * PN + s) * C + ch;
    o1[0] = m0;
    o1[1] = m1;

    // vertices_pool
    if (t < 3) {
        out[(size_t)(b * PN + s) * 3 + t] = vb[q * 3 + t];
    }
}

extern "C" void kernel_launch(void* const* d_in, const int* in_sizes, int n_in,
                              void* d_out, int out_size, void* d_ws, size_t ws_size,
                              hipStream_t stream) {
    const float* vert = (const float*)d_in[0];
    const float* feat = (const float*)d_in[1];
    const int*   sidx = (const int*)d_in[2];
    float* out = (float*)d_out;

    pool_knn_kernel<<<BS * PN, NT, 0, stream>>>(vert, feat, sidx, out);
}

// Round 2
// 175.161 us; speedup vs baseline: 1.1375x; 1.1375x over previous
//
#include <hip/hip_runtime.h>

#define BS 16
#define V  2048
#define C  512
#define PN 512
#define K  16
#define NT 256

typedef unsigned long long u64;

// u64 min with a DPP-fetched neighbor. old = own value, bound_ctrl=false:
// lanes whose DPP source is invalid (row edge) keep their own value, and
// min(x,x)=x, so no row/bank masking is needed (min is idempotent).
template<int CTRL>
__device__ __forceinline__ u64 u64_min_dpp(u64 x) {
    const int lo = (int)(unsigned)(x & 0xFFFFFFFFull);
    const int hi = (int)(unsigned)(x >> 32);
    const int nlo = __builtin_amdgcn_update_dpp(lo, lo, CTRL, 0xF, 0xF, false);
    const int nhi = __builtin_amdgcn_update_dpp(hi, hi, CTRL, 0xF, 0xF, false);
    const u64 n = ((u64)(unsigned)nhi << 32) | (unsigned)nlo;
    return n < x ? n : x;
}

// Full wave64 min, result broadcast uniform via readlane(63). VALU-only.
__device__ __forceinline__ u64 wave_min_u64(u64 x) {
    x = u64_min_dpp<0x111>(x);  // row_shr:1
    x = u64_min_dpp<0x112>(x);  // row_shr:2
    x = u64_min_dpp<0x114>(x);  // row_shr:4
    x = u64_min_dpp<0x118>(x);  // row_shr:8   -> lane15 of each row16 = row min
    x = u64_min_dpp<0x142>(x);  // row_bcast:15 -> lane31 = min(r0,r1), lane63 = min(r2,r3)
    x = u64_min_dpp<0x143>(x);  // row_bcast:31 -> lane63 = wave min
    const unsigned lo = (unsigned)__builtin_amdgcn_readlane((int)(unsigned)(x & 0xFFFFFFFFull), 63);
    const unsigned hi = (unsigned)__builtin_amdgcn_readlane((int)(unsigned)(x >> 32), 63);
    return ((u64)hi << 32) | lo;
}

// compare-exchange, literal indices only (stays in registers)
#define CE(i, j) { const bool p_ = kk[j] < kk[i]; const u64 a_ = p_ ? kk[j] : kk[i]; \
                   const u64 b_ = p_ ? kk[i] : kk[j]; kk[i] = a_; kk[j] = b_; }

__global__ __launch_bounds__(NT) void pool_knn_kernel(
    const float* __restrict__ vert,   // [BS, V, 3]
    const float* __restrict__ feat,   // [BS, V, C]
    const int*   __restrict__ sidx,   // [PN]
    float* __restrict__ out)          // [BS*PN*3] ++ [BS*PN*C]
{
    const int blk = blockIdx.x;
    const int b = blk >> 9;           // / PN
    const int s = blk & (PN - 1);
    const int t = threadIdx.x;
    const int wid = t >> 6;

    const int q = sidx[s];
    const float* vb = vert + (size_t)b * (V * 3);
    const float qx = vb[q * 3 + 0];
    const float qy = vb[q * 3 + 1];
    const float qz = vb[q * 3 + 2];
    const float qq = qx * qx + qy * qy + qz * qz;

    __shared__ u64 wlist[(NT / 64) * K];   // 4 waves x 16 winners = 512 B

    // ---- Phase 1: 8 distance keys per thread, in registers ----
    u64 kk[8];
    #pragma unroll
    for (int i = 0; i < 8; ++i) {
        const int m = i * NT + t;
        const float mx = vb[m * 3 + 0];
        const float my = vb[m * 3 + 1];
        const float mz = vb[m * 3 + 2];
        const float qm = mx * mx + my * my + mz * mz;
        const float inner = qx * mx + qy * my + qz * mz;
        const float dist = (-2.0f * inner + qm) + qq;
        unsigned u = __float_as_uint(dist);
        u ^= (u & 0x80000000u) ? 0xFFFFFFFFu : 0x80000000u;  // order-preserving map
        const u64 key = ((u64)u << 32) | (unsigned)m;
        kk[i] = (m == q) ? ~0ULL : key;    // exclude self (== ref's drop-top-1)
    }

    // ---- sort the 8 keys ascending (optimal 19-CE network) ----
    CE(0,1) CE(2,3) CE(4,5) CE(6,7)
    CE(0,2) CE(1,3) CE(4,6) CE(5,7)
    CE(1,2) CE(5,6) CE(0,4) CE(3,7)
    CE(1,5) CE(2,6)
    CE(1,4) CE(3,6)
    CE(2,4) CE(3,5)
    CE(3,4)

    // ---- Phase 2a: per-wave top-16 of its 512, no barriers, no LDS scans ----
    for (int r = 0; r < K; ++r) {
        const u64 wm = wave_min_u64(kk[0]);
        if ((t & 63) == 0) wlist[wid * K + r] = wm;
        const bool w_ = (kk[0] == wm);     // unique keys -> exactly one winner
        kk[0] = w_ ? kk[1] : kk[0];
        kk[1] = w_ ? kk[2] : kk[1];
        kk[2] = w_ ? kk[3] : kk[2];
        kk[3] = w_ ? kk[4] : kk[3];
        kk[4] = w_ ? kk[5] : kk[4];
        kk[5] = w_ ? kk[6] : kk[5];
        kk[6] = w_ ? kk[7] : kk[6];
        kk[7] = w_ ? ~0ULL : kk[7];
    }
    __syncthreads();

    // ---- Phase 2b: every wave redundantly merges 4x16 -> global top-16.
    // Winners come back via readlane => uniform (SGPR) indices for phase 3.
    u64 cand = wlist[t & 63];
    int nidx[K];
    #pragma unroll
    for (int r = 0; r < K; ++r) {
        const u64 wm = wave_min_u64(cand);
        nidx[r] = (int)(unsigned)(wm & 0xFFFFFFFFull);
        cand = (cand == wm) ? ~0ULL : cand;
    }

    // ---- Phase 3: gather 16 rows (uniform row base) + channel-wise max ----
    const float* fb = feat + (size_t)b * (V * C);
    const int ch = t * 2;
    float m0 = -__builtin_inff(), m1 = -__builtin_inff();
    #pragma unroll
    for (int r = 0; r < K; ++r) {
        const float2 f = *reinterpret_cast<const float2*>(fb + (size_t)nidx[r] * C + ch);
        m0 = fmaxf(m0, f.x);
        m1 = fmaxf(m1, f.y);
    }
    float* o1 = out + (size_t)BS * PN * 3 + (size_t)(b * PN + s) * C + ch;
    o1[0] = m0;
    o1[1] = m1;

    if (t < 3) {
        out[(size_t)(b * PN + s) * 3 + t] = vb[q * 3 + t];
    }
}

extern "C" void kernel_launch(void* const* d_in, const int* in_sizes, int n_in,
                              void* d_out, int out_size, void* d_ws, size_t ws_size,
                              hipStream_t stream) {
    const float* vert = (const float*)d_in[0];
    const float* feat = (const float*)d_in[1];
    const int*   sidx = (const int*)d_in[2];
    float* out = (float*)d_out;

    pool_knn_kernel<<<BS * PN, NT, 0, stream>>>(vert, feat, sidx, out);
}

// Round 4
// 143.129 us; speedup vs baseline: 1.3921x; 1.2238x over previous
//
#include <hip/hip_runtime.h>

#define BS 16
#define V  2048
#define C  512
#define PN 512
#define K  16
#define NT 256

typedef unsigned long long u64;
typedef unsigned int u32;

// --- wave64 min over u32, VALU-only (v_min_u32 with DPP), result uniform ---
template<int CTRL>
__device__ __forceinline__ u32 min_dpp_u32(u32 x) {
    const u32 n = (u32)__builtin_amdgcn_update_dpp((int)x, (int)x, CTRL, 0xF, 0xF, false);
    return n < x ? n : x;   // bound_ctrl=false keeps own value at row edges; min idempotent
}
__device__ __forceinline__ u32 wave_min_u32(u32 x) {
    x = min_dpp_u32<0x111>(x);  // row_shr:1
    x = min_dpp_u32<0x112>(x);  // row_shr:2
    x = min_dpp_u32<0x114>(x);  // row_shr:4
    x = min_dpp_u32<0x118>(x);  // row_shr:8   -> lane{15,31,47,63} = row mins
    x = min_dpp_u32<0x142>(x);  // row_bcast:15
    x = min_dpp_u32<0x143>(x);  // row_bcast:31 -> lane63 = wave min
    return (u32)__builtin_amdgcn_readlane((int)x, 63);
}
__device__ __forceinline__ int mbcnt64(u64 m) {   // popcount of mask bits below my lane
    return __builtin_amdgcn_mbcnt_hi((u32)(m >> 32),
           __builtin_amdgcn_mbcnt_lo((u32)m, 0));
}

// compare-exchange on u64 sort keys, literal indices only (stays in registers)
#define CE(i, j) { const bool p_ = sk[j] < sk[i]; const u64 a_ = p_ ? sk[j] : sk[i]; \
                   const u64 b_ = p_ ? sk[i] : sk[j]; sk[i] = a_; sk[j] = b_; }

__global__ __launch_bounds__(NT) void pool_knn_kernel(
    const float* __restrict__ vert,   // [BS, V, 3]
    const float* __restrict__ feat,   // [BS, V, C]
    const int*   __restrict__ sidx,   // [PN]
    float* __restrict__ out)          // [BS*PN*3] ++ [BS*PN*C]
{
    const int blk = blockIdx.x;
    const int b = blk >> 9;            // / PN
    const int s = blk & (PN - 1);
    const int t = threadIdx.x;
    const int wid = t >> 6;
    const int lane = t & 63;
    const u32 wbase = (u32)wid * 512u; // this wave's point range

    const int q = sidx[s];
    const float* vb = vert + (size_t)b * (V * 3);
    const float qx = vb[q * 3 + 0];
    const float qy = vb[q * 3 + 1];
    const float qz = vb[q * 3 + 2];
    const float qq = qx * qx + qy * qy + qz * qz;

    __shared__ u64 wlist[(NT / 64) * K];   // 4 waves x 16 winner keys
    __shared__ int nbr[K];                 // final 16 neighbor indices (set order)

    // ---- Phase 1: 8 distances/thread; sort (dist, slot) pairs; keep
    //      u32 dists + 4-bit slot permutation (m = wbase + slot*64 + lane) ----
    u32 d0, d1, d2, d3, d4, d5, d6, d7, perm;
    {
        u64 sk[8];
        #pragma unroll
        for (int i = 0; i < 8; ++i) {
            const int m = (int)wbase + i * 64 + lane;
            const float mx = vb[m * 3 + 0];
            const float my = vb[m * 3 + 1];
            const float mz = vb[m * 3 + 2];
            const float qm = mx * mx + my * my + mz * mz;
            const float inner = qx * mx + qy * my + qz * mz;
            const float dist = (-2.0f * inner + qm) + qq;   // exact ref ordering
            u32 u = __float_as_uint(dist);
            u ^= (u & 0x80000000u) ? 0xFFFFFFFFu : 0x80000000u;  // monotone map
            if (m == q) u = 0xFFFFFFFFu;                          // exclude self
            sk[i] = ((u64)u << 32) | (u32)i;                      // tie-break: slot == m order
        }
        // optimal 19-CE sorting network, ascending by (dist, slot)
        CE(0,1) CE(2,3) CE(4,5) CE(6,7)
        CE(0,2) CE(1,3) CE(4,6) CE(5,7)
        CE(1,2) CE(5,6) CE(0,4) CE(3,7)
        CE(1,5) CE(2,6)
        CE(1,4) CE(3,6)
        CE(2,4) CE(3,5)
        CE(3,4)
        d0 = (u32)(sk[0] >> 32); d1 = (u32)(sk[1] >> 32);
        d2 = (u32)(sk[2] >> 32); d3 = (u32)(sk[3] >> 32);
        d4 = (u32)(sk[4] >> 32); d5 = (u32)(sk[5] >> 32);
        d6 = (u32)(sk[6] >> 32); d7 = (u32)(sk[7] >> 32);
        perm = (u32)sk[0]        | ((u32)sk[1] << 4)  | ((u32)sk[2] << 8)  |
               ((u32)sk[3] << 12)| ((u32)sk[4] << 16) | ((u32)sk[5] << 20) |
               ((u32)sk[6] << 24)| ((u32)sk[7] << 28);
    }

    // ---- Phase 2a: per-wave top-16 SET via u32-dist wave-min rounds.
    //      Multiplicity-aware; exact (dist, idx) order enforced only where it
    //      can matter (slot-boundary ties -> rare path; hidden same-lane
    //      duplicates guarded by the d1==wm ballot). ----
    {
        int r = 0;
        while (r < K) {
            const u32 wm = wave_min_u32(d0);
            const bool pred = (d0 == wm);
            const u64 mask = __ballot(pred);
            const int cnt = (int)__popcll(mask);
            const u64 hid = __ballot(d1 == wm);   // same-lane duplicate of wm?
            if ((r + cnt <= K) && (hid == 0ull)) {
                if (pred) {
                    const u32 idx = wbase + ((perm & 15u) << 6) + (u32)lane;
                    wlist[wid * K + r + mbcnt64(mask)] = ((u64)d0 << 32) | idx;
                }
                d0 = pred ? d1 : d0; d1 = pred ? d2 : d1; d2 = pred ? d3 : d2;
                d3 = pred ? d4 : d3; d4 = pred ? d5 : d4; d5 = pred ? d6 : d5;
                d6 = pred ? d7 : d6; d7 = pred ? 0xFFFFFFFFu : d7;
                perm = pred ? (perm >> 4) : perm;
                r += cnt;
            } else {
                // exact single pop: among tied fronts, smallest index wins
                const u32 myidx = pred ? (wbase + ((perm & 15u) << 6) + (u32)lane)
                                       : 0xFFFFFFFFu;
                const u32 wi = wave_min_u32(myidx);
                const bool w2 = pred && (myidx == wi);
                if (w2) wlist[wid * K + r] = ((u64)d0 << 32) | myidx;
                d0 = w2 ? d1 : d0; d1 = w2 ? d2 : d1; d2 = w2 ? d3 : d2;
                d3 = w2 ? d4 : d3; d4 = w2 ? d5 : d4; d5 = w2 ? d6 : d5;
                d6 = w2 ? d7 : d6; d7 = w2 ? 0xFFFFFFFFu : d7;
                perm = w2 ? (perm >> 4) : perm;
                r += 1;
            }
        }
    }
    __syncthreads();

    // ---- Phase 2b: wave 0 merges 4x16 candidates -> global top-16 set ----
    if (wid == 0) {
        const u64 ck = wlist[lane];
        u32 cd = (u32)(ck >> 32);
        const u32 ci = (u32)ck;
        int r = 0;
        while (r < K) {
            const u32 wm = wave_min_u32(cd);
            const bool pred = (cd == wm);
            const u64 mask = __ballot(pred);
            const int cnt = (int)__popcll(mask);
            if (r + cnt <= K) {                 // 1 elem/lane -> no hidden dups
                if (pred) nbr[r + mbcnt64(mask)] = (int)ci;
                cd = pred ? 0xFFFFFFFFu : cd;
                r += cnt;
            } else {
                const u32 mi = pred ? ci : 0xFFFFFFFFu;
                const u32 wi = wave_min_u32(mi);
                const bool w2 = pred && (ci == wi);
                if (w2) nbr[r] = (int)ci;
                cd = w2 ? 0xFFFFFFFFu : cd;
                r += 1;
            }
        }
    }
    __syncthreads();

    // ---- Phase 3: gather 16 rows (scalar row base via readfirstlane) + max ----
    const float* fb = feat + (size_t)b * (V * C);
    const int ch = t * 2;
    float m0 = -__builtin_inff(), m1 = -__builtin_inff();
    #pragma unroll
    for (int r = 0; r < K; ++r) {
        const int idx = __builtin_amdgcn_readfirstlane(nbr[r]);
        const float2 f = *reinterpret_cast<const float2*>(fb + (size_t)idx * C + ch);
        m0 = fmaxf(m0, f.x);
        m1 = fmaxf(m1, f.y);
    }
    float* o1 = out + (size_t)BS * PN * 3 + (size_t)(b * PN + s) * C + ch;
    o1[0] = m0;
    o1[1] = m1;

    if (t < 3) {
        out[(size_t)(b * PN + s) * 3 + t] = vb[q * 3 + t];
    }
}

extern "C" void kernel_launch(void* const* d_in, const int* in_sizes, int n_in,
                              void* d_out, int out_size, void* d_ws, size_t ws_size,
                              hipStream_t stream) {
    const float* vert = (const float*)d_in[0];
    const float* feat = (const float*)d_in[1];
    const int*   sidx = (const int*)d_in[2];
    float* out = (float*)d_out;

    pool_knn_kernel<<<BS * PN, NT, 0, stream>>>(vert, feat, sidx, out);
}

// Round 6
// 129.784 us; speedup vs baseline: 1.5352x; 1.1028x over previous
//
#include <hip/hip_runtime.h>

#define BS 16
#define V  2048
#define C  512
#define PN 512
#define K  16
#define NT 256

typedef unsigned long long u64;
typedef unsigned int u32;

// --- wave64 min over u32, VALU-only (v_min_u32 + DPP), result uniform ---
template<int CTRL>
__device__ __forceinline__ u32 min_dpp_u32(u32 x) {
    const u32 n = (u32)__builtin_amdgcn_update_dpp((int)x, (int)x, CTRL, 0xF, 0xF, false);
    return n < x ? n : x;   // bound_ctrl=false: edge lanes keep own value; min idempotent
}
__device__ __forceinline__ u32 wave_min_u32(u32 x) {
    x = min_dpp_u32<0x111>(x);  // row_shr:1
    x = min_dpp_u32<0x112>(x);  // row_shr:2
    x = min_dpp_u32<0x114>(x);  // row_shr:4
    x = min_dpp_u32<0x118>(x);  // row_shr:8
    x = min_dpp_u32<0x142>(x);  // row_bcast:15
    x = min_dpp_u32<0x143>(x);  // row_bcast:31 -> lane63 = wave min
    return (u32)__builtin_amdgcn_readlane((int)x, 63);
}
// u64 max with DPP (row_ror rotate-reduce; rotation has no invalid lanes)
template<int CTRL>
__device__ __forceinline__ u64 max_dpp_u64(u64 x) {
    const int lo = (int)(u32)x, hi = (int)(u32)(x >> 32);
    const int plo = __builtin_amdgcn_update_dpp(lo, lo, CTRL, 0xF, 0xF, false);
    const int phi = __builtin_amdgcn_update_dpp(hi, hi, CTRL, 0xF, 0xF, false);
    const u64 p = ((u64)(u32)phi << 32) | (u32)plo;
    return p > x ? p : x;
}
// u64 cross-lane fetch via ds_swizzle (BitMode: xor<<10 | and=0x1F); 32-lane groups
template<int OFS>
__device__ __forceinline__ u64 swz_u64(u64 x) {
    const int lo = __builtin_amdgcn_ds_swizzle((int)(u32)x, OFS);
    const int hi = __builtin_amdgcn_ds_swizzle((int)(u32)(x >> 32), OFS);
    return ((u64)(u32)hi << 32) | (u32)lo;
}
// one bitonic-merge stage at distance D (partner = lane XOR D), ascending
template<int D, int OFS>
__device__ __forceinline__ u64 bitonic_stage(u64 x, int ll) {
    const u64 p = swz_u64<OFS>(x);
    const bool keepmin = ((ll & D) == 0);
    const bool pl = (p < x);
    const bool takep = keepmin ? pl : !pl;   // keys unique -> p!=x where it matters
    return takep ? p : x;
}
__device__ __forceinline__ int mbcnt64(u64 m) {
    return __builtin_amdgcn_mbcnt_hi((u32)(m >> 32),
           __builtin_amdgcn_mbcnt_lo((u32)m, 0));
}

// compare-exchange on u64 sort keys (register-resident, literal indices)
#define CE(i, j) { const bool p_ = sk[j] < sk[i]; const u64 a_ = p_ ? sk[j] : sk[i]; \
                   const u64 b_ = p_ ? sk[i] : sk[j]; sk[i] = a_; sk[j] = b_; }

// one exact pop: pops the lex-min (dist,idx) of the wave's frontier into wlist[slot].
// Single-pop always (never multi-pop) -> wlist runs are lex-sorted, as the
// bitonic merge requires. Tie cases (cnt>1 or same-lane dup) take the exact
// min-idx path. Returns via reference-modified d0..d7/perm.
#define POP_ONE(SLOT)                                                          \
    {                                                                          \
        const u32 wm = wave_min_u32(d0);                                       \
        const bool pred = (d0 == wm);                                          \
        const u64 mask = __ballot(pred);                                       \
        const int cnt = (int)__popcll(mask);                                   \
        const u64 hid = __ballot(d1 == wm);                                    \
        bool w_;                                                               \
        if ((cnt == 1) && (hid == 0ull)) {                                     \
            w_ = pred;                                                         \
        } else {                                                               \
            const u32 myidx = pred ? (wbase + ((perm & 15u) << 6) + (u32)lane) \
                                   : 0xFFFFFFFFu;                              \
            const u32 wi = wave_min_u32(myidx);                                \
            w_ = pred && (myidx == wi);                                        \
        }                                                                      \
        if (w_) {                                                              \
            const u32 idx = wbase + ((perm & 15u) << 6) + (u32)lane;           \
            wlist[wid * 16 + (SLOT)] = ((u64)d0 << 32) | idx;                  \
        }                                                                      \
        d0 = w_ ? d1 : d0; d1 = w_ ? d2 : d1; d2 = w_ ? d3 : d2;               \
        d3 = w_ ? d4 : d3; d4 = w_ ? d5 : d4; d5 = w_ ? d6 : d5;               \
        d6 = w_ ? d7 : d6; d7 = w_ ? 0xFFFFFFFFu : d7;                         \
        perm = w_ ? (perm >> 4) : perm;                                        \
    }

__global__ __launch_bounds__(NT) void pool_knn_kernel(
    const float* __restrict__ vert,   // [BS, V, 3]
    const float* __restrict__ feat,   // [BS, V, C]
    const int*   __restrict__ sidx,   // [PN]
    float* __restrict__ out)          // [BS*PN*3] ++ [BS*PN*C]
{
    const int blk = blockIdx.x;
    const int b = blk >> 9;            // / PN
    const int s = blk & (PN - 1);
    const int t = threadIdx.x;
    const int wid = t >> 6;
    const int lane = t & 63;
    const u32 wbase = (u32)wid * 512u;

    __shared__ u64 wlist[64];          // 4 waves x up-to-16 offered keys
    __shared__ int nbr[K];             // resume path only
    __shared__ int flagw;
    __shared__ int cntw[4];
    if (t == 0) flagw = 0;
    if (t < 4) cntw[t] = 8;

    const int q = sidx[s];
    const float* vb = vert + (size_t)b * (V * 3);
    const float qx = vb[q * 3 + 0];
    const float qy = vb[q * 3 + 1];
    const float qz = vb[q * 3 + 2];
    const float qq = qx * qx + qy * qy + qz * qz;

    // ---- Phase 1: 8 distances/thread; sort (dist, slot); keep u32 dists +
    //      nibble slot-permutation (idx = wbase + slot*64 + lane) ----
    u32 d0, d1, d2, d3, d4, d5, d6, d7, perm;
    {
        u64 sk[8];
        #pragma unroll
        for (int i = 0; i < 8; ++i) {
            const int m = (int)wbase + i * 64 + lane;
            const float mx = vb[m * 3 + 0];
            const float my = vb[m * 3 + 1];
            const float mz = vb[m * 3 + 2];
            const float qm = mx * mx + my * my + mz * mz;
            const float inner = qx * mx + qy * my + qz * mz;
            const float dist = (-2.0f * inner + qm) + qq;   // exact ref ordering
            u32 u = __float_as_uint(dist);
            u ^= (u & 0x80000000u) ? 0xFFFFFFFFu : 0x80000000u;  // monotone map
            if (m == q) u = 0xFFFFFFFFu;                          // exclude self
            sk[i] = ((u64)u << 32) | (u32)i;   // tie-break by slot == idx order
        }
        CE(0,1) CE(2,3) CE(4,5) CE(6,7)
        CE(0,2) CE(1,3) CE(4,6) CE(5,7)
        CE(1,2) CE(5,6) CE(0,4) CE(3,7)
        CE(1,5) CE(2,6)
        CE(1,4) CE(3,6)
        CE(2,4) CE(3,5)
        CE(3,4)
        d0 = (u32)(sk[0] >> 32); d1 = (u32)(sk[1] >> 32);
        d2 = (u32)(sk[2] >> 32); d3 = (u32)(sk[3] >> 32);
        d4 = (u32)(sk[4] >> 32); d5 = (u32)(sk[5] >> 32);
        d6 = (u32)(sk[6] >> 32); d7 = (u32)(sk[7] >> 32);
        perm = (u32)sk[0]        | ((u32)sk[1] << 4)  | ((u32)sk[2] << 8)  |
               ((u32)sk[3] << 12)| ((u32)sk[4] << 16) | ((u32)sk[5] << 20) |
               ((u32)sk[6] << 24)| ((u32)sk[7] << 28);
    }

    // ---- Phase 2a: exactly 8 lex-ordered pops per wave ----
    #pragma unroll
    for (int r = 0; r < 8; ++r) { POP_ONE(r) }
    __syncthreads();                       // barrier 1: wlist published

    // ---- Phase 2b: bitonic merge of 4 sorted-8 runs -> top-16 set in lanes
    //      0..15 (all waves redundantly; winners stay in registers) ----
    u64 x;
    {
        const int w = lane >> 3;                         // run id (lane<32)
        const int rr = (w & 1) ? (7 - (lane & 7)) : (lane & 7);  // reverse odd runs
        const int addr = (w & 3) * 16 + rr;
        const u64 ld = wlist[(lane < 32) ? addr : 0];
        x = (lane < 32) ? ld : ~0ULL;
        const int ll = lane & 15;
        x = bitonic_stage<8, 0x201F>(x, ll);   // xor 8
        x = bitonic_stage<4, 0x101F>(x, ll);   // xor 4
        x = bitonic_stage<2, 0x081F>(x, ll);   // xor 2
        x = bitonic_stage<1, 0x041F>(x, ll);   // xor 1
        // lanes0-15 = sorted S (R0∪R1), lanes16-31 = sorted T (R2∪R3)
        const u64 p = swz_u64<0x7C1F>(x);      // xor 31: S_i <-> T_{15-i}
        x = (p < x) ? p : x;                   // lanes0-15: exact top-16 set
    }

    // ---- validation: B16 = max winner key; wave resumes iff its 8th-offered
    //      key < B16 (stale-B16 >= true g16 -> rule is exact) ----
    u64 B16;
    {
        u64 bm = (lane < 16) ? x : 0ULL;
        bm = max_dpp_u64<0x121>(bm);  // row_ror:1  (within row16)
        bm = max_dpp_u64<0x122>(bm);  // row_ror:2
        bm = max_dpp_u64<0x124>(bm);  // row_ror:4
        bm = max_dpp_u64<0x128>(bm);  // row_ror:8
        const u32 blo = (u32)__builtin_amdgcn_readlane((int)(u32)bm, 0);
        const u32 bhi = (u32)__builtin_amdgcn_readlane((int)(u32)(bm >> 32), 0);
        B16 = ((u64)bhi << 32) | blo;
    }
    const u64 k8 = wlist[wid * 16 + 7];        // wave's 8th pop (uniform addr)
    const int resu = __builtin_amdgcn_readfirstlane((int)(k8 < B16));
    if (resu && lane == 0) flagw = 1;          // benign same-value race
    __syncthreads();                           // barrier 2

    int nidx[K];
    if (flagw != 0) {
        // ---- rare exact path (~3% of blocks): offending waves pop until
        //      frontier key > B16 (cap 16 total: no wave can contribute >16) ----
        if (resu) {
            int r = 8;
            while (r < 16) {
                const u32 fm = wave_min_u32(d0);
                if (((u64)fm << 32) > B16) break;   // unpopped keys all > B16 >= g16
                POP_ONE(r)
                ++r;
            }
            if (lane == 0) cntw[wid] = r;
        }
        __syncthreads();                       // barrier 3
        if (wid == 0) {
            // exact 16-pop set-merge over up-to-64 candidates (validity-masked)
            const int cv = cntw[lane >> 4];
            const u64 ck = ((lane & 15) < cv) ? wlist[lane] : ~0ULL;
            u32 cd = (u32)(ck >> 32);
            const u32 ci = (u32)ck;
            int r = 0;
            while (r < K) {
                const u32 wm = wave_min_u32(cd);
                const bool pred = (cd == wm);
                const u64 mask = __ballot(pred);
                const int cnt = (int)__popcll(mask);
                if (r + cnt <= K) {
                    if (pred) nbr[r + mbcnt64(mask)] = (int)ci;
                    cd = pred ? 0xFFFFFFFFu : cd;
                    r += cnt;
                } else {
                    const u32 mi = pred ? ci : 0xFFFFFFFFu;
                    const u32 wi = wave_min_u32(mi);
                    const bool w2 = pred && (ci == wi);
                    if (w2) nbr[r] = (int)ci;
                    cd = w2 ? 0xFFFFFFFFu : cd;
                    r += 1;
                }
            }
        }
        __syncthreads();                       // barrier 4
        #pragma unroll
        for (int r = 0; r < K; ++r)
            nidx[r] = __builtin_amdgcn_readfirstlane(nbr[r]);
    } else {
        // ---- common path: winners already in registers of every wave ----
        const int xlo = (int)(u32)x;           // low 32 = idx
        #pragma unroll
        for (int r = 0; r < K; ++r)
            nidx[r] = __builtin_amdgcn_readlane(xlo, r);
    }

    // ---- Phase 3: gather 16 rows (scalar row bases) + channel-wise max ----
    const float* fb = feat + (size_t)b * (V * C);
    const int ch = t * 2;
    float m0 = -__builtin_inff(), m1 = -__builtin_inff();
    #pragma unroll
    for (int r = 0; r < K; ++r) {
        const float2 f = *reinterpret_cast<const float2*>(fb + (size_t)nidx[r] * C + ch);
        m0 = fmaxf(m0, f.x);
        m1 = fmaxf(m1, f.y);
    }
    float* o1 = out + (size_t)BS * PN * 3 + (size_t)(b * PN + s) * C + ch;
    o1[0] = m0;
    o1[1] = m1;

    if (t < 3) {
        out[(size_t)(b * PN + s) * 3 + t] = vb[q * 3 + t];
    }
}

extern "C" void kernel_launch(void* const* d_in, const int* in_sizes, int n_in,
                              void* d_out, int out_size, void* d_ws, size_t ws_size,
                              hipStream_t stream) {
    const float* vert = (const float*)d_in[0];
    const float* feat = (const float*)d_in[1];
    const int*   sidx = (const int*)d_in[2];
    float* out = (float*)d_out;

    pool_knn_kernel<<<BS * PN, NT, 0, stream>>>(vert, feat, sidx, out);
}